// Round 1
// baseline (303.317 us; speedup 1.0000x reference)
//
#include <hip/hip_runtime.h>
#include <hip/hip_bf16.h>

#define HH 128
#define EE 256
#define KK 4
#define RR 8
#define LL 2
#define BB 2
#define SS 1024
#define BT (BB*SS)      // 2048 tokens total
#define NJ (RR+2*HH)    // 264 dbc rows
#define EPS 1e-5f
#define LOG2E 1.44269504088896f

__device__ __forceinline__ float silu_f(float v) {
    return v / (1.0f + __expf(-v));
}

// ---------------- K1: rmsnorm + in_proj (+bias) -> xz [2048][512] ------------
__global__ __launch_bounds__(512) void k_norm_inproj(
    const float* __restrict__ xres, const float* __restrict__ inw,
    const float* __restrict__ inb, const float* __restrict__ nw,
    float* __restrict__ xz)
{
    __shared__ float xn[16][128];
    const int bt0 = blockIdx.x * 16;
    const int tid = threadIdx.x;
    {   // phase A: rmsnorm for 16 tokens, 32 threads per token
        const int t = tid >> 5, g = tid & 31;
        const float4 xv = *(const float4*)(xres + (bt0 + t) * HH + g * 4);
        float ss = xv.x*xv.x + xv.y*xv.y + xv.z*xv.z + xv.w*xv.w;
        #pragma unroll
        for (int m = 16; m >= 1; m >>= 1) ss += __shfl_xor(ss, m);
        const float rs = rsqrtf(ss * (1.0f / HH) + EPS);
        const float4 wv = *(const float4*)(nw + g * 4);
        float4 o;
        o.x = xv.x * rs * wv.x; o.y = xv.y * rs * wv.y;
        o.z = xv.z * rs * wv.z; o.w = xv.w * rs * wv.w;
        *(float4*)(&xn[t][g * 4]) = o;
    }
    __syncthreads();
    // phase B: thread = output column j (512), 16-token accumulators
    const int j = tid;
    float acc[16];
    const float bj = inb[j];
    #pragma unroll
    for (int t = 0; t < 16; t++) acc[t] = bj;
    for (int k4 = 0; k4 < 32; k4++) {
        const int k = k4 * 4;
        const float w0 = inw[(k+0)*512 + j], w1 = inw[(k+1)*512 + j];
        const float w2 = inw[(k+2)*512 + j], w3 = inw[(k+3)*512 + j];
        #pragma unroll
        for (int t = 0; t < 16; t++) {
            const float4 xv = *(const float4*)(&xn[t][k]);
            acc[t] += w0*xv.x + w1*xv.y + w2*xv.z + w3*xv.w;
        }
    }
    #pragma unroll
    for (int t = 0; t < 16; t++) xz[(bt0 + t) * 512 + j] = acc[t];
}

// ---------------- K2A: causal conv + silu -> xcT [256][2048] -----------------
__global__ __launch_bounds__(256) void k_conv(
    const float* __restrict__ xz, const float* __restrict__ cw,
    const float* __restrict__ cb, float* __restrict__ xcT)
{
    const int e = threadIdx.x;
    const int tile = blockIdx.x;          // 32 tiles of 64 tokens, within-batch
    const int b = tile >> 4;
    const int t0 = (tile & 15) * 64;
    const float w0 = cw[e*4+0], w1 = cw[e*4+1], w2 = cw[e*4+2], w3 = cw[e*4+3];
    const float bias = cb[e];
    const float* xp = xz + (size_t)(b * SS) * 512 + e;  // index token via *512
    float xm3 = (t0 >= 3) ? xp[(t0-3)*512] : 0.0f;
    float xm2 = (t0 >= 2) ? xp[(t0-2)*512] : 0.0f;
    float xm1 = (t0 >= 1) ? xp[(t0-1)*512] : 0.0f;
    float* orow = xcT + (size_t)e * BT + b * SS + t0;
    for (int jq = 0; jq < 16; jq++) {
        const int t = t0 + jq * 4;
        float4 ob; float v;
        const float x0 = xp[(t+0)*512];
        v = bias + w3*x0 + w2*xm1 + w1*xm2 + w0*xm3; ob.x = silu_f(v);
        const float x1 = xp[(t+1)*512];
        v = bias + w3*x1 + w2*x0 + w1*xm1 + w0*xm2;  ob.y = silu_f(v);
        const float x2 = xp[(t+2)*512];
        v = bias + w3*x2 + w2*x1 + w1*x0 + w0*xm1;   ob.z = silu_f(v);
        const float x3 = xp[(t+3)*512];
        v = bias + w3*x3 + w2*x2 + w1*x1 + w0*x0;    ob.w = silu_f(v);
        *(float4*)(orow + jq * 4) = ob;
        xm3 = x1; xm2 = x2; xm1 = x3;
    }
}

// ---------------- K2B: pl_proj -> dbcT [264][2048] ---------------------------
__global__ __launch_bounds__(320) void k_plproj(
    const float* __restrict__ xcT, const float* __restrict__ plw,
    const float* __restrict__ plb, float* __restrict__ dbcT)
{
    __shared__ float xs[8][256];
    const int bt0 = blockIdx.x * 8;
    const int tid = threadIdx.x;
    if (tid < 256) {
        const int e = tid;
        const float* p = xcT + (size_t)e * BT + bt0;
        const float4 a = *(const float4*)(p);
        const float4 c = *(const float4*)(p + 4);
        xs[0][e] = a.x; xs[1][e] = a.y; xs[2][e] = a.z; xs[3][e] = a.w;
        xs[4][e] = c.x; xs[5][e] = c.y; xs[6][e] = c.z; xs[7][e] = c.w;
    }
    __syncthreads();
    if (tid >= NJ) return;
    const int j = tid;
    float acc[8];
    const float bj = plb[j];
    #pragma unroll
    for (int t = 0; t < 8; t++) acc[t] = bj;
    for (int e4 = 0; e4 < 64; e4++) {
        const int e = e4 * 4;
        const float w0 = plw[(e+0)*NJ + j], w1 = plw[(e+1)*NJ + j];
        const float w2 = plw[(e+2)*NJ + j], w3 = plw[(e+3)*NJ + j];
        #pragma unroll
        for (int t = 0; t < 8; t++) {
            const float4 xv = *(const float4*)(&xs[t][e]);
            acc[t] += w0*xv.x + w1*xv.y + w2*xv.z + w3*xv.w;
        }
    }
    float* orow = dbcT + (size_t)j * BT + bt0;
    *(float4*)(orow)     = make_float4(acc[0], acc[1], acc[2], acc[3]);
    *(float4*)(orow + 4) = make_float4(acc[4], acc[5], acc[6], acc[7]);
}

// ---------------- K2C: delta = softplus(dt_proj), s = delta*xc ---------------
__global__ __launch_bounds__(256) void k_delta(
    const float* __restrict__ dbcT, const float* __restrict__ dtw,
    const float* __restrict__ dtb, const float* __restrict__ xcT,
    float* __restrict__ deltaT, float* __restrict__ sT)
{
    const int e = blockIdx.x >> 3;
    const int bt = (blockIdx.x & 7) * 256 + threadIdx.x;
    float d = dtb[e];
    #pragma unroll
    for (int r = 0; r < RR; r++) d += dtw[r*EE + e] * dbcT[(size_t)r * BT + bt];
    float sp;
    if (d > 15.0f) sp = d;
    else sp = log1pf(__expf(d));
    const float xc = xcT[(size_t)e * BT + bt];
    deltaT[(size_t)e * BT + bt] = sp;
    sT[(size_t)e * BT + bt] = sp * xc;
}

// ---------------- K3: selective scan -> yT [256][2048] -----------------------
__global__ __launch_bounds__(128) void k_scan(
    const float* __restrict__ dbcT, const float* __restrict__ deltaT,
    const float* __restrict__ sT, const float* __restrict__ Alog,
    float* __restrict__ yT)
{
    __shared__ float part[64][129];
    __shared__ float red2[64][2];
    __shared__ float ybuf[1024];
    const int b = blockIdx.x >> 8;
    const int e = blockIdx.x & 255;
    const int n = threadIdx.x;                 // state index 0..127
    const float An = -__expf(Alog[e * HH + n]) * LOG2E;   // pre-scaled for exp2
    const float* Brow = dbcT + (size_t)(RR + n) * BT + b * SS;
    const float* Crow = dbcT + (size_t)(RR + HH + n) * BT + b * SS;
    const float* drow = deltaT + (size_t)e * BT + b * SS;
    const float* srow = sT + (size_t)e * BT + b * SS;
    float h = 0.0f;
    const int half = n >> 6;
    const int tl = n & 63;
    for (int c = 0; c < 16; c++) {
        const int base = c * 64;
        for (int q = 0; q < 16; q++) {
            const int t = base + q * 4;
            const float4 d4 = *(const float4*)(drow + t);
            const float4 s4 = *(const float4*)(srow + t);
            const float4 b4 = *(const float4*)(Brow + t);
            const float4 c4 = *(const float4*)(Crow + t);
            float a;
            a = exp2f(d4.x * An); h = a*h + s4.x*b4.x; part[q*4+0][n] = h*c4.x;
            a = exp2f(d4.y * An); h = a*h + s4.y*b4.y; part[q*4+1][n] = h*c4.y;
            a = exp2f(d4.z * An); h = a*h + s4.z*b4.z; part[q*4+2][n] = h*c4.z;
            a = exp2f(d4.w * An); h = a*h + s4.w*b4.w; part[q*4+3][n] = h*c4.w;
        }
        __syncthreads();
        // reduce 128 partials per timestep: thread (tl, half) sums 64 entries
        float s0 = 0, s1 = 0, s2 = 0, s3 = 0;
        #pragma unroll
        for (int i = 0; i < 16; i++) {
            const float4 p = *(const float4*)(&part[tl][half * 64 + i * 4]);
            s0 += p.x; s1 += p.y; s2 += p.z; s3 += p.w;
        }
        red2[tl][half] = (s0 + s1) + (s2 + s3);
        __syncthreads();
        if (n < 64) ybuf[base + n] = red2[n][0] + red2[n][1];
        __syncthreads();
    }
    float* yrow = yT + (size_t)e * BT + b * SS;
    #pragma unroll
    for (int i = 0; i < 8; i++) yrow[n + i * 128] = ybuf[n + i * 128];
}

// ---------------- K4: gate + out_proj + residual (in-place xres) -------------
__global__ __launch_bounds__(256) void k_gate_outproj(
    const float* __restrict__ yT, const float* __restrict__ xcT,
    const float* __restrict__ xz, const float* __restrict__ Dp,
    const float* __restrict__ ow, const float* __restrict__ ob,
    float* __restrict__ xres)
{
    __shared__ float gs[16][256];
    __shared__ float part2[16][128];
    const int bt0 = blockIdx.x * 16;
    const int tid = threadIdx.x;
    {   // phase A: g = (y + Dp*xc) * silu(skip)
        const int e = tid;
        const float dp = Dp[e];
        const float* yp = yT + (size_t)e * BT + bt0;
        const float* xp = xcT + (size_t)e * BT + bt0;
        #pragma unroll
        for (int tq = 0; tq < 4; tq++) {
            const float4 y4 = *(const float4*)(yp + tq * 4);
            const float4 x4 = *(const float4*)(xp + tq * 4);
            const float yv0 = y4.x, yv1 = y4.y, yv2 = y4.z, yv3 = y4.w;
            const float xv0 = x4.x, xv1 = x4.y, xv2 = x4.z, xv3 = x4.w;
            float sk;
            sk = xz[(size_t)(bt0 + tq*4 + 0) * 512 + 256 + e];
            gs[tq*4+0][e] = (yv0 + dp * xv0) * silu_f(sk);
            sk = xz[(size_t)(bt0 + tq*4 + 1) * 512 + 256 + e];
            gs[tq*4+1][e] = (yv1 + dp * xv1) * silu_f(sk);
            sk = xz[(size_t)(bt0 + tq*4 + 2) * 512 + 256 + e];
            gs[tq*4+2][e] = (yv2 + dp * xv2) * silu_f(sk);
            sk = xz[(size_t)(bt0 + tq*4 + 3) * 512 + 256 + e];
            gs[tq*4+3][e] = (yv3 + dp * xv3) * silu_f(sk);
        }
    }
    __syncthreads();
    // phase B: split-K GEMM, thread = (j, kh)
    const int j = tid & 127;
    const int kh = tid >> 7;
    float acc[16];
    #pragma unroll
    for (int t = 0; t < 16; t++) acc[t] = 0.0f;
    for (int e4 = 0; e4 < 32; e4++) {
        const int e = kh * 128 + e4 * 4;
        const float w0 = ow[(e+0)*HH + j], w1 = ow[(e+1)*HH + j];
        const float w2 = ow[(e+2)*HH + j], w3 = ow[(e+3)*HH + j];
        #pragma unroll
        for (int t = 0; t < 16; t++) {
            const float4 g4 = *(const float4*)(&gs[t][e]);
            acc[t] += w0*g4.x + w1*g4.y + w2*g4.z + w3*g4.w;
        }
    }
    if (kh == 1) {
        #pragma unroll
        for (int t = 0; t < 16; t++) part2[t][j] = acc[t];
    }
    __syncthreads();
    if (kh == 0) {
        const float bj = ob[j];
        #pragma unroll
        for (int t = 0; t < 16; t++) {
            const float r = acc[t] + part2[t][j] + bj
                          + xres[(size_t)(bt0 + t) * HH + j];
            xres[(size_t)(bt0 + t) * HH + j] = r;
        }
    }
}

// ---------------- K5: final rmsnorm -> d_out ---------------------------------
__global__ __launch_bounds__(64) void k_finalnorm(
    const float* __restrict__ xres, const float* __restrict__ fw,
    float* __restrict__ out)
{
    const int bt = blockIdx.x;
    const int tid = threadIdx.x;
    const float2 v = *(const float2*)(xres + (size_t)bt * HH + tid * 2);
    float ss = v.x*v.x + v.y*v.y;
    #pragma unroll
    for (int m = 32; m >= 1; m >>= 1) ss += __shfl_xor(ss, m);
    const float rs = rsqrtf(ss * (1.0f / HH) + EPS);
    const float2 w = *(const float2*)(fw + tid * 2);
    float2 o; o.x = v.x * rs * w.x; o.y = v.y * rs * w.y;
    *(float2*)(out + (size_t)bt * HH + tid * 2) = o;
}

extern "C" void kernel_launch(void* const* d_in, const int* in_sizes, int n_in,
                              void* d_out, int out_size, void* d_ws, size_t ws_size,
                              hipStream_t stream)
{
    const float* x      = (const float*)d_in[0];
    const float* in_w   = (const float*)d_in[1];
    const float* in_b   = (const float*)d_in[2];
    const float* out_w  = (const float*)d_in[3];
    const float* out_b  = (const float*)d_in[4];
    const float* pl_w   = (const float*)d_in[5];
    const float* pl_b   = (const float*)d_in[6];
    const float* dt_w   = (const float*)d_in[7];
    const float* dt_b   = (const float*)d_in[8];
    const float* conv_w = (const float*)d_in[9];
    const float* conv_b = (const float*)d_in[10];
    const float* A_log  = (const float*)d_in[11];
    const float* Dp     = (const float*)d_in[12];
    const float* norm_w = (const float*)d_in[13];
    const float* fnw    = (const float*)d_in[14];

    float* ws     = (float*)d_ws;
    float* xres   = ws;                        // 262144
    float* xz     = xres   + 262144;           // 1048576
    float* xcT    = xz     + 1048576;          // 524288
    float* dbcT   = xcT    + 524288;           // 540672
    float* deltaT = dbcT   + 540672;           // 524288
    float* sT     = deltaT + 524288;           // 524288
    float* yT     = sT     + 524288;           // 524288  (total ~15.8 MB)

    hipMemcpyAsync(xres, x, (size_t)262144 * sizeof(float),
                   hipMemcpyDeviceToDevice, stream);

    for (int l = 0; l < LL; l++) {
        k_norm_inproj<<<BT/16, 512, 0, stream>>>(
            xres, in_w + (size_t)l*HH*2*EE, in_b + (size_t)l*2*EE,
            norm_w + (size_t)l*HH, xz);
        k_conv<<<32, 256, 0, stream>>>(
            xz, conv_w + (size_t)l*EE*KK, conv_b + (size_t)l*EE, xcT);
        k_plproj<<<BT/8, 320, 0, stream>>>(
            xcT, pl_w + (size_t)l*EE*NJ, pl_b + (size_t)l*NJ, dbcT);
        k_delta<<<EE*8, 256, 0, stream>>>(
            dbcT, dt_w + (size_t)l*RR*EE, dt_b + (size_t)l*EE, xcT, deltaT, sT);
        k_scan<<<BB*EE, 128, 0, stream>>>(
            dbcT, deltaT, sT, A_log + (size_t)l*EE*HH, yT);
        k_gate_outproj<<<BT/16, 256, 0, stream>>>(
            yT, xcT, xz, Dp + (size_t)l*EE,
            out_w + (size_t)l*EE*HH, out_b + (size_t)l*HH, xres);
    }
    k_finalnorm<<<BT, 64, 0, stream>>>(xres, fnw, (float*)d_out);
}